// Round 17
// baseline (1305.008 us; speedup 1.0000x reference)
//
#include <hip/hip_runtime.h>
#include <math.h>

#define QD 6
#define LTC 10
#define NW 8192
#define NT (NW + LTC)      // 8202
#define D60 60
#define MI 256
#define JITTER 1e-6f
#define LOG2E 1.4426950408889634f

typedef __attribute__((ext_vector_type(8))) short bf16x8;
typedef __attribute__((ext_vector_type(4))) float f32x4;

// ws layout (float offsets)
#define OFF_W      0                       // 8192*64
#define OFF_SLOG   524288                  // 8192*256 (reused post-k_acc: KT/GT)
#define OFF_ACC    (OFF_SLOG + 2097152)    // 65536
#define OFF_KUU    (OFF_ACC + 65536)
#define OFF_G      (OFF_KUU + 65536)
#define OFF_PSI2   (OFF_G + 65536)
#define OFF_RPART  (OFF_PSI2 + 65536)      // 512*256*6
#define OFF_R      (OFF_RPART + 786432)    // 1536
#define OFF_SCAL   (OFF_R + 1536)          // 16 (floats; [8..15] = k_acc work-queue ints)
#define OFF_TI1    (OFF_SCAL + 16)         // 65536
// aliases into dead Slog region (only used after k_acc completes):
#define OFF_KT     OFF_SLOG                // 65536
#define OFF_GT     (OFF_SLOG + 65536)      // 65536
// scal: 0 sumXvo, 1 sumXmo2, 2 sumlogXvo, 3 summb, 4 trace_raw, 5 ldK, 6 ldG

__device__ __forceinline__ ushort f2bf(float f) {
    union { float f; unsigned u; } x; x.f = f;
    unsigned r = x.u + 0x7fffu + ((x.u >> 16) & 1u);
    return (ushort)(r >> 16);
}
__device__ __forceinline__ float bf2f(ushort h) {
    return __uint_as_float(((unsigned)h) << 16);
}
__device__ __forceinline__ unsigned cvt_pk_bf16(float a, float b) {
    unsigned r;
    asm("v_cvt_pk_bf16_f32 %0, %1, %2" : "=v"(r) : "v"(a), "v"(b));
    return r;   // lo16 = bf16(a), hi16 = bf16(b), RNE
}

// prep: fused {acc zeroing, reduce_x (blocks<64)}, wave-local phase-1, 1 barrier, phase-2
__global__ __launch_bounds__(256) void k_prep(const float* __restrict__ Xm, const float* __restrict__ Xv,
                                              const float* __restrict__ Zg, const float* __restrict__ kvar,
                                              const float* __restrict__ klen,
                                              float* __restrict__ W, float* __restrict__ Slog,
                                              float* __restrict__ rpart,
                                              float* __restrict__ accz, float* __restrict__ scal) {
    __shared__ float Zt[D60][MI];            // 61.4 KB
    __shared__ float4 quadS[16][D60];        // {w*mu, w, 1/(S+l2), mu}
    __shared__ float sldS[16][2];
    __shared__ float xmoS[16][QD];
    __shared__ float redx[4][4];
    const int t = threadIdx.x;
    // fused acc zeroing (512 blocks x 128 = 65536)
    if (t < 128) accz[blockIdx.x * 128 + t] = 0.f;
    // fused reduce_x (blocks 0..63 only; block-uniform barrier use)
    if (blockIdx.x < 64) {
        float s0 = 0.f, s1 = 0.f, s2 = 0.f, s3 = 0.f;
        const int tot = NT * QD;
        for (int i = blockIdx.x * 256 + t; i < tot; i += 64 * 256) {
            float xm = Xm[i], xv = Xv[i];
            if (i >= LTC * QD) { s0 += xv; s1 += xm * xm; s2 += __logf(xv); }
            else { s3 += xm * xm + xv; }
        }
        #pragma unroll
        for (int o = 32; o; o >>= 1) {
            s0 += __shfl_down(s0, o); s1 += __shfl_down(s1, o);
            s2 += __shfl_down(s2, o); s3 += __shfl_down(s3, o);
        }
        if ((t & 63) == 0) { int w = t >> 6; redx[0][w] = s0; redx[1][w] = s1; redx[2][w] = s2; redx[3][w] = s3; }
        __syncthreads();
        if (t == 0) {
            float a0 = 0, a1 = 0, a2 = 0, a3 = 0;
            for (int w = 0; w < 4; ++w) { a0 += redx[0][w]; a1 += redx[1][w]; a2 += redx[2][w]; a3 += redx[3][w]; }
            unsafeAtomicAdd(&scal[0], a0); unsafeAtomicAdd(&scal[1], a1);
            unsafeAtomicAdd(&scal[2], a2); unsafeAtomicAdd(&scal[3], a3);
        }
    }
    const float sf2 = kvar[0];
    const float l = klen[0];
    const float l2 = l * l;
    for (int idx = t; idx < D60 * MI; idx += 256) {
        int d = idx >> 8, m = idx & 255;
        Zt[d][m] = Zg[m * D60 + d];
    }
    const int n0 = blockIdx.x * 16;
    const int wv = t >> 6, lane = t & 63;
    #pragma unroll
    for (int i = 0; i < 4; ++i) {
        const int nn = wv * 4 + i;
        const int n = n0 + nn;
        float lt1 = 0.f, lt2 = 0.f, e1 = 0.f;
        if (lane < D60) {
            float S = Xv[n * QD + lane], mu = Xm[n * QD + lane];
            float w = 1.0f / (2.0f * S + l2);
            float invd1 = 1.0f / (S + l2);
            quadS[nn][lane] = make_float4(w * mu, w, invd1, mu);
            W[n * 64 + lane] = -0.5f * LOG2E * w;
            lt1 = __logf(1.0f + S / l2);
            lt2 = __logf(1.0f + 2.0f * S / l2);
            e1 = w * mu * mu;
        } else {
            W[n * 64 + lane] = 0.f;
        }
        if (lane < QD) xmoS[nn][lane] = Xm[n * QD + D60 + lane];
        #pragma unroll
        for (int o = 32; o; o >>= 1) {
            lt1 += __shfl_down(lt1, o); lt2 += __shfl_down(lt2, o); e1 += __shfl_down(e1, o);
        }
        if (lane == 0) { sldS[nn][0] = -0.5f * lt1; sldS[nn][1] = 0.5f * (-0.5f * lt2 - e1); }
    }
    __syncthreads();
    float r6[QD];
    #pragma unroll
    for (int q = 0; q < QD; ++q) r6[q] = 0.f;
    for (int nn = 0; nn < 16; ++nn) {
        const int n = n0 + nn;
        float e2 = 0.f, e3 = 0.f, q1 = 0.f;
        #pragma unroll 10
        for (int d = 0; d < D60; ++d) {
            float4 qd = quadS[nn][d];
            float z = Zt[d][t];
            e2 += qd.x * z;
            e3 += qd.y * z * z;
            float dm = qd.w - z;
            q1 += dm * dm * qd.z;
        }
        Slog[n * MI + t] = sldS[nn][1] + e2 - 0.25f * e3;
        float psi1 = sf2 * __expf(sldS[nn][0] - 0.5f * q1);
        #pragma unroll
        for (int q = 0; q < QD; ++q) r6[q] += psi1 * xmoS[nn][q];
    }
    #pragma unroll
    for (int q = 0; q < QD; ++q) rpart[(blockIdx.x * MI + t) * QD + q] = r6[q];
}

// main: acc[m,p] += sum_n exp2( LOG2E*(Slog_a+Slog_b) - LOG2E*e4 ), e4 via split-bf16 3-pass
// MFMA. zr[] asm-pinned (anti-remat); W window in LDS; Slog in-loop; launch_bounds(256,2).
__global__ __launch_bounds__(256, 2) void k_acc(const float* __restrict__ Zg, const float* __restrict__ W,
                                                const float* __restrict__ Slog, float* __restrict__ acc,
                                                int* __restrict__ q) {
    __shared__ ushort Ah[128 * 64];   // 16 KB, XOR-swizzled rows
    __shared__ ushort Al[128 * 64];   // 16 KB
    __shared__ float Wlds[64 * 64];   // 16 KB: W[n0+nn][d]
    __shared__ float saa[128], sbb[64];
    __shared__ int wksh;
    const int t = threadIdx.x;
    if (t == 0) {
        int xcc = (int)(__builtin_amdgcn_s_getreg((31 << 11) | 20)) & 7;   // HW_REG_XCC_ID
        int work = 0;
        #pragma unroll 1
        for (int a = 0; a < 8; ++a) {
            int p = (xcc + a) & 7;
            int tk = atomicAdd(&q[p], 1);
            if (tk < 96) { work = p * 96 + tk; break; }
        }
        wksh = work;
    }
    __syncthreads();
    const int wk = wksh;
    const int nc = wk / 6;
    const int tile = wk % 6;
    const int m0 = (tile < 4) ? 0 : 128;
    const int p0 = (tile < 4) ? tile * 64 : 128 + (tile - 4) * 64;
    const int lane = t & 63, wid = t >> 6;
    const int wr = wid >> 1, wc = wid & 1;
    const int sm = t & 127, kh = t >> 7;
    const int n0 = nc * 64;

    float zr[32];
    #pragma unroll
    for (int j = 0; j < 32; ++j) {
        int k = kh * 32 + j;
        zr[j] = (k < D60) ? Zg[(m0 + sm) * D60 + k] : 0.f;
        asm volatile("" : "+v"(zr[j]));
    }
    for (int idx = t; idx < 64 * 64; idx += 256)
        Wlds[idx] = W[n0 * 64 + idx];
    for (int idx = t; idx < 64 * 64; idx += 256) {
        int p = idx >> 6, k = idx & 63;
        float v = (k < D60) ? Zg[(p0 + p) * D60 + k] : 0.f;
        ushort hi = f2bf(v);
        ushort lo = f2bf(v - bf2f(hi));
        int byte = p * 128 + ((k * 2) ^ ((p & 7) << 4));
        *(ushort*)((char*)Ah + byte) = hi;
        *(ushort*)((char*)Al + byte) = lo;
    }
    __syncthreads();
    bf16x8 bh[2][2], bl[2][2];
    #pragma unroll
    for (int ct = 0; ct < 2; ++ct) {
        int p = 32 * wc + 16 * ct + (lane & 15);
        int swz = (p & 7) << 4;
        #pragma unroll
        for (int h = 0; h < 2; ++h) {
            int byte = p * 128 + ((((lane >> 4) * 16) + 64 * h) ^ swz);
            bh[ct][h] = *(const bf16x8*)((const char*)Ah + byte);
            bl[ct][h] = *(const bf16x8*)((const char*)Al + byte);
        }
    }

    float accr[4][2][4];
    #pragma unroll
    for (int a = 0; a < 4; ++a)
        #pragma unroll
        for (int b = 0; b < 2; ++b)
            #pragma unroll
            for (int c = 0; c < 4; ++c) accr[a][b][c] = 0.f;

    for (int nn = 0; nn < 64; ++nn) {
        const int n = n0 + nn;
        __syncthreads();   // previous compute done reading Ah/Al
        {
            const float* wrow = Wlds + nn * 64 + kh * 32;
            float av[32];
            #pragma unroll
            for (int j = 0; j < 8; ++j) {
                float4 f = *(const float4*)(wrow + 4 * j);
                av[4 * j + 0] = f.x * zr[4 * j + 0];
                av[4 * j + 1] = f.y * zr[4 * j + 1];
                av[4 * j + 2] = f.z * zr[4 * j + 2];
                av[4 * j + 3] = f.w * zr[4 * j + 3];
            }
            unsigned pkh[16], pkl[16];
            #pragma unroll
            for (int j = 0; j < 16; ++j) {
                float v0 = av[2 * j], v1 = av[2 * j + 1];
                unsigned ph = cvt_pk_bf16(v0, v1);
                float h0 = __uint_as_float(ph << 16);
                float h1 = __uint_as_float(ph & 0xffff0000u);
                pkh[j] = ph;
                pkl[j] = cvt_pk_bf16(v0 - h0, v1 - h1);
            }
            #pragma unroll
            for (int cc = 0; cc < 4; ++cc) {
                int byte = sm * 128 + (((kh * 64) + cc * 16) ^ ((sm & 7) << 4));
                uint4 vh; vh.x = pkh[4 * cc]; vh.y = pkh[4 * cc + 1]; vh.z = pkh[4 * cc + 2]; vh.w = pkh[4 * cc + 3];
                uint4 vl; vl.x = pkl[4 * cc]; vl.y = pkl[4 * cc + 1]; vl.z = pkl[4 * cc + 2]; vl.w = pkl[4 * cc + 3];
                *(uint4*)((char*)Ah + byte) = vh;
                *(uint4*)((char*)Al + byte) = vl;
            }
            if (t < 128) saa[t] = LOG2E * Slog[n * MI + m0 + t];
            else if (t < 192) sbb[t - 128] = LOG2E * Slog[n * MI + p0 + (t - 128)];
        }
        __syncthreads();
        float sbv[2];
        #pragma unroll
        for (int ct = 0; ct < 2; ++ct) sbv[ct] = sbb[32 * wc + 16 * ct + (lane & 15)];
        #pragma unroll
        for (int rt = 0; rt < 4; ++rt) {
            int m = 64 * wr + 16 * rt + (lane & 15);
            int swz = (m & 7) << 4;
            bf16x8 ah0 = *(const bf16x8*)((const char*)Ah + m * 128 + (((lane >> 4) * 16) ^ swz));
            bf16x8 ah1 = *(const bf16x8*)((const char*)Ah + m * 128 + ((64 + (lane >> 4) * 16) ^ swz));
            bf16x8 al0 = *(const bf16x8*)((const char*)Al + m * 128 + (((lane >> 4) * 16) ^ swz));
            bf16x8 al1 = *(const bf16x8*)((const char*)Al + m * 128 + ((64 + (lane >> 4) * 16) ^ swz));
            float sav[4];
            int rbase = 64 * wr + 16 * rt + (lane >> 4) * 4;
            #pragma unroll
            for (int rr = 0; rr < 4; ++rr) sav[rr] = saa[rbase + rr];
            #pragma unroll
            for (int ct = 0; ct < 2; ++ct) {
                f32x4 d;
                #pragma unroll
                for (int rr = 0; rr < 4; ++rr) d[rr] = sav[rr] + sbv[ct];
                d = __builtin_amdgcn_mfma_f32_16x16x32_bf16(ah0, bh[ct][0], d, 0, 0, 0);
                d = __builtin_amdgcn_mfma_f32_16x16x32_bf16(ah1, bh[ct][1], d, 0, 0, 0);
                d = __builtin_amdgcn_mfma_f32_16x16x32_bf16(ah0, bl[ct][0], d, 0, 0, 0);
                d = __builtin_amdgcn_mfma_f32_16x16x32_bf16(ah1, bl[ct][1], d, 0, 0, 0);
                d = __builtin_amdgcn_mfma_f32_16x16x32_bf16(al0, bh[ct][0], d, 0, 0, 0);
                d = __builtin_amdgcn_mfma_f32_16x16x32_bf16(al1, bh[ct][1], d, 0, 0, 0);
                #pragma unroll
                for (int rr = 0; rr < 4; ++rr)
                    accr[rt][ct][rr] += exp2f(d[rr]);
            }
        }
    }
    #pragma unroll
    for (int rt = 0; rt < 4; ++rt)
        #pragma unroll
        for (int ct = 0; ct < 2; ++ct)
            #pragma unroll
            for (int rr = 0; rr < 4; ++rr) {
                int row = m0 + 64 * wr + 16 * rt + (lane >> 4) * 4 + rr;
                int col = p0 + 32 * wc + 16 * ct + (lane & 15);
                unsafeAtomicAdd(&acc[row * MI + col], accr[rt][ct][rr]);
            }
}

// psi2/Kuu/G build (blocks 0..255) fused with reduce_r (blocks 256..261)
__global__ __launch_bounds__(256) void k_psi2r(const float* __restrict__ Zg, const float* __restrict__ kvar,
                                               const float* __restrict__ klen, const float* __restrict__ lvar,
                                               const float* __restrict__ acc, float* __restrict__ psi2,
                                               float* __restrict__ Kuu, float* __restrict__ G,
                                               const float* __restrict__ rpart, float* __restrict__ r) {
    if (blockIdx.x >= 256) {
        int idx = (blockIdx.x - 256) * 256 + threadIdx.x;   // 0..1535
        if (idx < 1536) {
            float s = 0.f;
            for (int b = 0; b < 512; ++b) s += rpart[b * 1536 + idx];
            r[idx] = s;
        }
        return;
    }
    __shared__ float zi[D60];
    const int i = blockIdx.x, j = threadIdx.x;
    if (j < D60) zi[j] = Zg[i * D60 + j];
    __syncthreads();
    const float sf2 = kvar[0];
    const float l = klen[0];
    const float l2 = l * l;
    const float sigma2 = lvar[0];
    float zz = 0.f;
    #pragma unroll 10
    for (int d = 0; d < D60; ++d) {
        float dz = zi[d] - Zg[j * D60 + d];
        zz += dz * dz;
    }
    float accv = (i < 128 || j >= 128) ? acc[i * MI + j] : acc[j * MI + i];
    float p2 = sf2 * sf2 * __expf(-zz / (4.f * l2)) * accv;
    psi2[i * MI + j] = p2;
    float kv = sf2 * __expf(-0.5f * zz / l2) + ((i == j) ? JITTER : 0.f);
    Kuu[i * MI + j] = kv;
    G[i * MI + j] = kv + p2 / sigma2;
}

// concurrent 2-matrix Cholesky. Elimination work is tiny (~127k MAC/panel) but was paying
// 248 block barriers; now ONE WAVE does each panel's 31-step elimination wave-synchronously
// (intra-wave program order + compiler lgkmcnt waits = zero barriers). Trailing update (the
// real n^3/3 FLOPs) stays on all 1024 threads. 3 barriers/panel.
__global__ __launch_bounds__(1024) void k_chol2(float* __restrict__ A0, float* __restrict__ A1,
                                                float* __restrict__ At0, float* __restrict__ At1,
                                                float* __restrict__ scal) {
    float* A  = blockIdx.x ? A1 : A0;
    float* At = blockIdx.x ? At1 : At0;
    __shared__ float Pt[32][MI];   // Pt[c][r] = A[p+r][p+c]
    __shared__ float dsh[32];      // 1/d_jj
    const int t = threadIdx.x;
    const int lane = t & 63;
    float lgacc = 0.f;
    for (int p = 0; p < MI; p += 32) {
        const int R = MI - p;
        for (int idx = t; idx < R * 32; idx += 1024) {
            int c = idx / R, rr = idx % R;
            Pt[c][rr] = A[(p + rr) * MI + (p + c)];
        }
        __syncthreads();
        // ---- wave-0 wave-synchronous unscaled elimination (no barriers) ----
        if (t < 64) {
            #pragma unroll 1
            for (int jj = 0; jj < 31; ++jj) {
                const float invd = 1.0f / fmaxf(Pt[jj][jj], 1e-20f);
                const int rows = R - jj - 1, ncols = 31 - jj;
                const int tot = rows * ncols;
                #pragma unroll 1
                for (int idx = lane; idx < tot; idx += 64) {
                    int c = jj + 1 + idx / rows;
                    int rr = jj + 1 + idx % rows;
                    Pt[c][rr] -= Pt[jj][rr] * (Pt[jj][c] * invd);
                }
            }
        }
        __syncthreads();
        if (t < 32) {
            float d = fmaxf(Pt[t][t], 1e-20f);
            dsh[t] = 1.0f / d;
            lgacc += __logf(d);
        }
        for (int idx = t; idx < R * 32; idx += 1024) {
            int c = idx / R, rr = idx % R;
            if (rr >= c) {
                float rs = rsqrtf(fmaxf(Pt[c][c], 1e-20f));
                At[(p + c) * MI + (p + rr)] = Pt[c][rr] * rs;
            }
        }
        __syncthreads();
        const int T = R - 32;
        if (T > 0) {
            const int BT = T >> 2;
            const int nb = BT * (BT + 1) / 2;
            for (int b = t; b < nb; b += 1024) {
                int br = (int)((sqrtf(8.0f * b + 1.0f) - 1.0f) * 0.5f);
                while ((br + 1) * (br + 2) / 2 <= b) ++br;
                while (br * (br + 1) / 2 > b) --br;
                int bc = b - br * (br + 1) / 2;
                int r0 = 32 + br * 4, c0 = 32 + bc * 4;
                float s[4][4];
                #pragma unroll
                for (int i = 0; i < 4; ++i)
                    #pragma unroll
                    for (int j = 0; j < 4; ++j) s[i][j] = 0.f;
                #pragma unroll 8
                for (int kk = 0; kk < 32; ++kk) {
                    float idk = dsh[kk];
                    float4 av = *(const float4*)(&Pt[kk][r0]);
                    float4 bv = *(const float4*)(&Pt[kk][c0]);
                    float aa[4] = {av.x, av.y, av.z, av.w};
                    float bb[4] = {bv.x * idk, bv.y * idk, bv.z * idk, bv.w * idk};
                    #pragma unroll
                    for (int i = 0; i < 4; ++i)
                        #pragma unroll
                        for (int j = 0; j < 4; ++j) s[i][j] += aa[i] * bb[j];
                }
                #pragma unroll
                for (int i = 0; i < 4; ++i)
                    #pragma unroll
                    for (int j = 0; j < 4; ++j)
                        A[(p + r0 + i) * MI + (p + c0 + j)] -= s[i][j];
            }
        }
        __syncthreads();
    }
    if (t < 32) {
        float v = lgacc;
        #pragma unroll
        for (int o = 16; o; o >>= 1) v += __shfl_down(v, o);
        if (t == 0) scal[5 + blockIdx.x] = v;   // = sum log d = 2*sum log diag(L)
    }
}

// wave-parallel forward triangular solve: L x = b for NQ RHS, single 64-lane wave,
// lane owns rows 4*lane..4*lane+3. At = L^T (coalesced column access). Returns sum of x^2.
template<int NQ, bool WTI>
__device__ __forceinline__ float tri_fwd(const float* __restrict__ At, float* __restrict__ Ti,
                                         int j0, float (&acc)[4][NQ]) {
    const int lane = threadIdx.x & 63;
    const int r0 = lane * 4;
    float invd[4];
    #pragma unroll
    for (int s = 0; s < 4; ++s) invd[s] = 1.0f / At[(r0 + s) * MI + (r0 + s)];
    float4 col[4];
    #pragma unroll
    for (int s = 0; s < 4; ++s) col[s] = *(const float4*)(At + (j0 + s) * MI + r0);
    float cs = 0.f;
    for (int i4 = j0; i4 < MI; i4 += 4) {
        float4 ncol[4];
        const bool more = (i4 + 4 < MI);
        #pragma unroll
        for (int s = 0; s < 4; ++s)
            ncol[s] = more ? *(const float4*)(At + (i4 + 4 + s) * MI + r0)
                           : make_float4(0.f, 0.f, 0.f, 0.f);
        #pragma unroll
        for (int S = 0; S < 4; ++S) {
            const int i = i4 + S;
            const int src = i >> 2;
            float xi[NQ];
            #pragma unroll
            for (int q = 0; q < NQ; ++q)
                xi[q] = __shfl(acc[S][q] * invd[S], src);
            if (WTI) {
                if (lane == src) {
                    #pragma unroll
                    for (int q = 0; q < NQ; ++q) Ti[i * MI + j0 + q] = xi[q];
                }
            }
            const float lv0 = col[S].x, lv1 = col[S].y, lv2 = col[S].z, lv3 = col[S].w;
            #pragma unroll
            for (int q = 0; q < NQ; ++q) {
                acc[0][q] -= lv0 * xi[q];
                acc[1][q] -= lv1 * xi[q];
                acc[2][q] -= lv2 * xi[q];
                acc[3][q] -= lv3 * xi[q];
                cs += xi[q] * xi[q];
            }
        }
        #pragma unroll
        for (int s = 0; s < 4; ++s) col[s] = ncol[s];
    }
    return cs;
}

// L^{-1} for Kuu: 16 blocks x 16 columns each. (Ti upper never read: tracedot guards.)
__global__ __launch_bounds__(64) void k_trinvK(const float* __restrict__ At, float* __restrict__ Ti) {
    const int lane = threadIdx.x;
    const int j0 = blockIdx.x * 16;
    const int r0 = lane * 4;
    float acc[4][16];
    #pragma unroll
    for (int s = 0; s < 4; ++s)
        #pragma unroll
        for (int q = 0; q < 16; ++q)
            acc[s][q] = (r0 + s == j0 + q) ? 1.f : 0.f;
    tri_fwd<16, true>(At, Ti, j0, acc);
}

// trace(Kuu^{-1} psi2) = sum_k v_k^T psi2 v_k, v_k = row k of Linv (lower; guard col>k)
__global__ __launch_bounds__(256) void k_tracedot(const float* __restrict__ Ti, const float* __restrict__ psi2,
                                                  float* __restrict__ scal) {
    __shared__ float vsh[MI];
    __shared__ float red[4];
    const int k = blockIdx.x, t = threadIdx.x;
    vsh[t] = Ti[k * MI + t];
    __syncthreads();
    float vj = (t <= k) ? vsh[t] : 0.f;
    float s = 0.f;
    for (int i = 0; i <= k; ++i) s += vsh[i] * psi2[i * MI + t];
    s *= vj;
    #pragma unroll
    for (int o = 32; o; o >>= 1) s += __shfl_down(s, o);
    if ((t & 63) == 0) red[t >> 6] = s;
    __syncthreads();
    if (t == 0) unsafeAtomicAdd(&scal[4], red[0] + red[1] + red[2] + red[3]);
}

// csum = sum_q || LG^{-1} r_q ||^2 via wave solve; lane 0 assembles final bound
__global__ __launch_bounds__(64) void k_solveG_final(const float* __restrict__ GT, const float* __restrict__ r,
                                                     const float* __restrict__ scal,
                                                     const float* __restrict__ kvar,
                                                     const float* __restrict__ lvar, const int* __restrict__ ltp,
                                                     float* __restrict__ out) {
    const int lane = threadIdx.x;
    const int r0 = lane * 4;
    float acc[4][QD];
    #pragma unroll
    for (int s = 0; s < 4; ++s)
        #pragma unroll
        for (int q = 0; q < QD; ++q)
            acc[s][q] = r[(r0 + s) * QD + q];
    float cs = tri_fwd<QD, false>(GT, nullptr, 0, acc);
    if (lane == 0) {
        double csum = (double)cs;
        double sigma2 = (double)lvar[0];
        double sf2 = (double)kvar[0];
        double two_pi = 6.283185307179586;
        double Nw = (double)NW, Q = (double)QD;
        double psi0 = Nw * sf2;
        double trace_AAT = (double)scal[4] / sigma2;
        double logdetB = (double)scal[6] - (double)scal[5];
        double bound = -0.5 * Nw * Q * log(two_pi * sigma2);
        bound += -0.5 / sigma2 * ((double)scal[0] + (double)scal[1]);
        bound += -0.5 * Q * (psi0 / sigma2 - trace_AAT);
        bound += -0.5 * Q * logdetB;
        bound += 0.5 * csum / (sigma2 * sigma2);
        bound += 0.5 * (double)scal[2] + Nw * Q * 0.5 * log(two_pi);
        bound += -(double)ltp[0] * Q * log(two_pi) - 0.5 * (double)scal[3];
        out[0] = (float)bound;
    }
}

extern "C" void kernel_launch(void* const* d_in, const int* in_sizes, int n_in,
                              void* d_out, int out_size, void* d_ws, size_t ws_size,
                              hipStream_t stream) {
    (void)in_sizes; (void)n_in; (void)out_size; (void)ws_size;
    const float* Xm = (const float*)d_in[0];
    const float* Xv = (const float*)d_in[1];
    const float* Zg = (const float*)d_in[2];
    const float* kvar = (const float*)d_in[3];
    const float* klen = (const float*)d_in[4];
    const float* lvar = (const float*)d_in[5];
    const int* ltp = (const int*)d_in[6];
    float* ws = (float*)d_ws;
    float* W = ws + OFF_W;
    float* Slog = ws + OFF_SLOG;
    float* acc = ws + OFF_ACC;
    float* Kuu = ws + OFF_KUU;
    float* G = ws + OFF_G;
    float* psi2 = ws + OFF_PSI2;
    float* rpart = ws + OFF_RPART;
    float* r = ws + OFF_R;
    float* scal = ws + OFF_SCAL;
    float* Ti1 = ws + OFF_TI1;
    float* KT = ws + OFF_KT;
    float* GT = ws + OFF_GT;

    hipMemsetAsync(scal, 0, 16 * sizeof(float), stream);   // includes q[8] at scal+8

    k_prep<<<512, 256, 0, stream>>>(Xm, Xv, Zg, kvar, klen, W, Slog, rpart, acc, scal);
    k_acc<<<768, 256, 0, stream>>>(Zg, W, Slog, acc, (int*)(scal + 8));
    k_psi2r<<<262, 256, 0, stream>>>(Zg, kvar, klen, lvar, acc, psi2, Kuu, G, rpart, r);
    k_chol2<<<2, 1024, 0, stream>>>(Kuu, G, KT, GT, scal);
    k_trinvK<<<16, 64, 0, stream>>>(KT, Ti1);
    k_tracedot<<<256, 256, 0, stream>>>(Ti1, psi2, scal);
    k_solveG_final<<<1, 64, 0, stream>>>(GT, r, scal, kvar, lvar, ltp, (float*)d_out);
}

// Round 18
// 673.191 us; speedup vs baseline: 1.9385x; 1.9385x over previous
//
#include <hip/hip_runtime.h>
#include <math.h>

#define QD 6
#define LTC 10
#define NW 8192
#define NT (NW + LTC)      // 8202
#define D60 60
#define MI 256
#define JITTER 1e-6f
#define LOG2E 1.4426950408889634f

typedef __attribute__((ext_vector_type(8))) short bf16x8;
typedef __attribute__((ext_vector_type(4))) float f32x4;

// ws layout (float offsets)
#define OFF_W      0                       // 8192*64
#define OFF_SLOG   524288                  // 8192*256 (reused post-k_acc: KT/GT)
#define OFF_ACC    (OFF_SLOG + 2097152)    // 65536
#define OFF_KUU    (OFF_ACC + 65536)
#define OFF_G      (OFF_KUU + 65536)
#define OFF_PSI2   (OFF_G + 65536)
#define OFF_RPART  (OFF_PSI2 + 65536)      // 512*256*6
#define OFF_R      (OFF_RPART + 786432)    // 1536
#define OFF_SCAL   (OFF_R + 1536)          // 16 (floats; [8..15] = k_acc work-queue ints)
#define OFF_TI1    (OFF_SCAL + 16)         // 65536
// aliases into dead Slog region (only used after k_acc completes):
#define OFF_KT     OFF_SLOG                // 65536
#define OFF_GT     (OFF_SLOG + 65536)      // 65536
// scal: 0 sumXvo, 1 sumXmo2, 2 sumlogXvo, 3 summb, 4 trace_raw, 5 ldK, 6 ldG

__device__ __forceinline__ ushort f2bf(float f) {
    union { float f; unsigned u; } x; x.f = f;
    unsigned r = x.u + 0x7fffu + ((x.u >> 16) & 1u);
    return (ushort)(r >> 16);
}
__device__ __forceinline__ float bf2f(ushort h) {
    return __uint_as_float(((unsigned)h) << 16);
}
__device__ __forceinline__ unsigned cvt_pk_bf16(float a, float b) {
    unsigned r;
    asm("v_cvt_pk_bf16_f32 %0, %1, %2" : "=v"(r) : "v"(a), "v"(b));
    return r;   // lo16 = bf16(a), hi16 = bf16(b), RNE
}

// prep: fused {acc zeroing, reduce_x (blocks<64)}, wave-local phase-1, 1 barrier, phase-2
__global__ __launch_bounds__(256) void k_prep(const float* __restrict__ Xm, const float* __restrict__ Xv,
                                              const float* __restrict__ Zg, const float* __restrict__ kvar,
                                              const float* __restrict__ klen,
                                              float* __restrict__ W, float* __restrict__ Slog,
                                              float* __restrict__ rpart,
                                              float* __restrict__ accz, float* __restrict__ scal) {
    __shared__ float Zt[D60][MI];            // 61.4 KB
    __shared__ float4 quadS[16][D60];        // {w*mu, w, 1/(S+l2), mu}
    __shared__ float sldS[16][2];
    __shared__ float xmoS[16][QD];
    __shared__ float redx[4][4];
    const int t = threadIdx.x;
    // fused acc zeroing (512 blocks x 128 = 65536)
    if (t < 128) accz[blockIdx.x * 128 + t] = 0.f;
    // fused reduce_x (blocks 0..63 only; block-uniform barrier use)
    if (blockIdx.x < 64) {
        float s0 = 0.f, s1 = 0.f, s2 = 0.f, s3 = 0.f;
        const int tot = NT * QD;
        for (int i = blockIdx.x * 256 + t; i < tot; i += 64 * 256) {
            float xm = Xm[i], xv = Xv[i];
            if (i >= LTC * QD) { s0 += xv; s1 += xm * xm; s2 += __logf(xv); }
            else { s3 += xm * xm + xv; }
        }
        #pragma unroll
        for (int o = 32; o; o >>= 1) {
            s0 += __shfl_down(s0, o); s1 += __shfl_down(s1, o);
            s2 += __shfl_down(s2, o); s3 += __shfl_down(s3, o);
        }
        if ((t & 63) == 0) { int w = t >> 6; redx[0][w] = s0; redx[1][w] = s1; redx[2][w] = s2; redx[3][w] = s3; }
        __syncthreads();
        if (t == 0) {
            float a0 = 0, a1 = 0, a2 = 0, a3 = 0;
            for (int w = 0; w < 4; ++w) { a0 += redx[0][w]; a1 += redx[1][w]; a2 += redx[2][w]; a3 += redx[3][w]; }
            unsafeAtomicAdd(&scal[0], a0); unsafeAtomicAdd(&scal[1], a1);
            unsafeAtomicAdd(&scal[2], a2); unsafeAtomicAdd(&scal[3], a3);
        }
    }
    const float sf2 = kvar[0];
    const float l = klen[0];
    const float l2 = l * l;
    for (int idx = t; idx < D60 * MI; idx += 256) {
        int d = idx >> 8, m = idx & 255;
        Zt[d][m] = Zg[m * D60 + d];
    }
    const int n0 = blockIdx.x * 16;
    const int wv = t >> 6, lane = t & 63;
    #pragma unroll
    for (int i = 0; i < 4; ++i) {
        const int nn = wv * 4 + i;
        const int n = n0 + nn;
        float lt1 = 0.f, lt2 = 0.f, e1 = 0.f;
        if (lane < D60) {
            float S = Xv[n * QD + lane], mu = Xm[n * QD + lane];
            float w = 1.0f / (2.0f * S + l2);
            float invd1 = 1.0f / (S + l2);
            quadS[nn][lane] = make_float4(w * mu, w, invd1, mu);
            W[n * 64 + lane] = -0.5f * LOG2E * w;
            lt1 = __logf(1.0f + S / l2);
            lt2 = __logf(1.0f + 2.0f * S / l2);
            e1 = w * mu * mu;
        } else {
            W[n * 64 + lane] = 0.f;
        }
        if (lane < QD) xmoS[nn][lane] = Xm[n * QD + D60 + lane];
        #pragma unroll
        for (int o = 32; o; o >>= 1) {
            lt1 += __shfl_down(lt1, o); lt2 += __shfl_down(lt2, o); e1 += __shfl_down(e1, o);
        }
        if (lane == 0) { sldS[nn][0] = -0.5f * lt1; sldS[nn][1] = 0.5f * (-0.5f * lt2 - e1); }
    }
    __syncthreads();
    float r6[QD];
    #pragma unroll
    for (int q = 0; q < QD; ++q) r6[q] = 0.f;
    for (int nn = 0; nn < 16; ++nn) {
        const int n = n0 + nn;
        float e2 = 0.f, e3 = 0.f, q1 = 0.f;
        #pragma unroll 10
        for (int d = 0; d < D60; ++d) {
            float4 qd = quadS[nn][d];
            float z = Zt[d][t];
            e2 += qd.x * z;
            e3 += qd.y * z * z;
            float dm = qd.w - z;
            q1 += dm * dm * qd.z;
        }
        Slog[n * MI + t] = sldS[nn][1] + e2 - 0.25f * e3;
        float psi1 = sf2 * __expf(sldS[nn][0] - 0.5f * q1);
        #pragma unroll
        for (int q = 0; q < QD; ++q) r6[q] += psi1 * xmoS[nn][q];
    }
    #pragma unroll
    for (int q = 0; q < QD; ++q) rpart[(blockIdx.x * MI + t) * QD + q] = r6[q];
}

// main: acc[m,p] += sum_n exp2( LOG2E*(Slog_a+Slog_b) - LOG2E*e4 ), e4 via split-bf16 3-pass
// MFMA. zr[] asm-pinned (anti-remat); W window in LDS; Slog in-loop; launch_bounds(256,2).
__global__ __launch_bounds__(256, 2) void k_acc(const float* __restrict__ Zg, const float* __restrict__ W,
                                                const float* __restrict__ Slog, float* __restrict__ acc,
                                                int* __restrict__ q) {
    __shared__ ushort Ah[128 * 64];   // 16 KB, XOR-swizzled rows
    __shared__ ushort Al[128 * 64];   // 16 KB
    __shared__ float Wlds[64 * 64];   // 16 KB: W[n0+nn][d]
    __shared__ float saa[128], sbb[64];
    __shared__ int wksh;
    const int t = threadIdx.x;
    if (t == 0) {
        int xcc = (int)(__builtin_amdgcn_s_getreg((31 << 11) | 20)) & 7;   // HW_REG_XCC_ID
        int work = 0;
        #pragma unroll 1
        for (int a = 0; a < 8; ++a) {
            int p = (xcc + a) & 7;
            int tk = atomicAdd(&q[p], 1);
            if (tk < 96) { work = p * 96 + tk; break; }
        }
        wksh = work;
    }
    __syncthreads();
    const int wk = wksh;
    const int nc = wk / 6;
    const int tile = wk % 6;
    const int m0 = (tile < 4) ? 0 : 128;
    const int p0 = (tile < 4) ? tile * 64 : 128 + (tile - 4) * 64;
    const int lane = t & 63, wid = t >> 6;
    const int wr = wid >> 1, wc = wid & 1;
    const int sm = t & 127, kh = t >> 7;
    const int n0 = nc * 64;

    float zr[32];
    #pragma unroll
    for (int j = 0; j < 32; ++j) {
        int k = kh * 32 + j;
        zr[j] = (k < D60) ? Zg[(m0 + sm) * D60 + k] : 0.f;
        asm volatile("" : "+v"(zr[j]));
    }
    for (int idx = t; idx < 64 * 64; idx += 256)
        Wlds[idx] = W[n0 * 64 + idx];
    for (int idx = t; idx < 64 * 64; idx += 256) {
        int p = idx >> 6, k = idx & 63;
        float v = (k < D60) ? Zg[(p0 + p) * D60 + k] : 0.f;
        ushort hi = f2bf(v);
        ushort lo = f2bf(v - bf2f(hi));
        int byte = p * 128 + ((k * 2) ^ ((p & 7) << 4));
        *(ushort*)((char*)Ah + byte) = hi;
        *(ushort*)((char*)Al + byte) = lo;
    }
    __syncthreads();
    bf16x8 bh[2][2], bl[2][2];
    #pragma unroll
    for (int ct = 0; ct < 2; ++ct) {
        int p = 32 * wc + 16 * ct + (lane & 15);
        int swz = (p & 7) << 4;
        #pragma unroll
        for (int h = 0; h < 2; ++h) {
            int byte = p * 128 + ((((lane >> 4) * 16) + 64 * h) ^ swz);
            bh[ct][h] = *(const bf16x8*)((const char*)Ah + byte);
            bl[ct][h] = *(const bf16x8*)((const char*)Al + byte);
        }
    }

    float accr[4][2][4];
    #pragma unroll
    for (int a = 0; a < 4; ++a)
        #pragma unroll
        for (int b = 0; b < 2; ++b)
            #pragma unroll
            for (int c = 0; c < 4; ++c) accr[a][b][c] = 0.f;

    for (int nn = 0; nn < 64; ++nn) {
        const int n = n0 + nn;
        __syncthreads();   // previous compute done reading Ah/Al
        {
            const float* wrow = Wlds + nn * 64 + kh * 32;
            float av[32];
            #pragma unroll
            for (int j = 0; j < 8; ++j) {
                float4 f = *(const float4*)(wrow + 4 * j);
                av[4 * j + 0] = f.x * zr[4 * j + 0];
                av[4 * j + 1] = f.y * zr[4 * j + 1];
                av[4 * j + 2] = f.z * zr[4 * j + 2];
                av[4 * j + 3] = f.w * zr[4 * j + 3];
            }
            unsigned pkh[16], pkl[16];
            #pragma unroll
            for (int j = 0; j < 16; ++j) {
                float v0 = av[2 * j], v1 = av[2 * j + 1];
                unsigned ph = cvt_pk_bf16(v0, v1);
                float h0 = __uint_as_float(ph << 16);
                float h1 = __uint_as_float(ph & 0xffff0000u);
                pkh[j] = ph;
                pkl[j] = cvt_pk_bf16(v0 - h0, v1 - h1);
            }
            #pragma unroll
            for (int cc = 0; cc < 4; ++cc) {
                int byte = sm * 128 + (((kh * 64) + cc * 16) ^ ((sm & 7) << 4));
                uint4 vh; vh.x = pkh[4 * cc]; vh.y = pkh[4 * cc + 1]; vh.z = pkh[4 * cc + 2]; vh.w = pkh[4 * cc + 3];
                uint4 vl; vl.x = pkl[4 * cc]; vl.y = pkl[4 * cc + 1]; vl.z = pkl[4 * cc + 2]; vl.w = pkl[4 * cc + 3];
                *(uint4*)((char*)Ah + byte) = vh;
                *(uint4*)((char*)Al + byte) = vl;
            }
            if (t < 128) saa[t] = LOG2E * Slog[n * MI + m0 + t];
            else if (t < 192) sbb[t - 128] = LOG2E * Slog[n * MI + p0 + (t - 128)];
        }
        __syncthreads();
        float sbv[2];
        #pragma unroll
        for (int ct = 0; ct < 2; ++ct) sbv[ct] = sbb[32 * wc + 16 * ct + (lane & 15)];
        #pragma unroll
        for (int rt = 0; rt < 4; ++rt) {
            int m = 64 * wr + 16 * rt + (lane & 15);
            int swz = (m & 7) << 4;
            bf16x8 ah0 = *(const bf16x8*)((const char*)Ah + m * 128 + (((lane >> 4) * 16) ^ swz));
            bf16x8 ah1 = *(const bf16x8*)((const char*)Ah + m * 128 + ((64 + (lane >> 4) * 16) ^ swz));
            bf16x8 al0 = *(const bf16x8*)((const char*)Al + m * 128 + (((lane >> 4) * 16) ^ swz));
            bf16x8 al1 = *(const bf16x8*)((const char*)Al + m * 128 + ((64 + (lane >> 4) * 16) ^ swz));
            float sav[4];
            int rbase = 64 * wr + 16 * rt + (lane >> 4) * 4;
            #pragma unroll
            for (int rr = 0; rr < 4; ++rr) sav[rr] = saa[rbase + rr];
            #pragma unroll
            for (int ct = 0; ct < 2; ++ct) {
                f32x4 d;
                #pragma unroll
                for (int rr = 0; rr < 4; ++rr) d[rr] = sav[rr] + sbv[ct];
                d = __builtin_amdgcn_mfma_f32_16x16x32_bf16(ah0, bh[ct][0], d, 0, 0, 0);
                d = __builtin_amdgcn_mfma_f32_16x16x32_bf16(ah1, bh[ct][1], d, 0, 0, 0);
                d = __builtin_amdgcn_mfma_f32_16x16x32_bf16(ah0, bl[ct][0], d, 0, 0, 0);
                d = __builtin_amdgcn_mfma_f32_16x16x32_bf16(ah1, bl[ct][1], d, 0, 0, 0);
                d = __builtin_amdgcn_mfma_f32_16x16x32_bf16(al0, bh[ct][0], d, 0, 0, 0);
                d = __builtin_amdgcn_mfma_f32_16x16x32_bf16(al1, bh[ct][1], d, 0, 0, 0);
                #pragma unroll
                for (int rr = 0; rr < 4; ++rr)
                    accr[rt][ct][rr] += exp2f(d[rr]);
            }
        }
    }
    #pragma unroll
    for (int rt = 0; rt < 4; ++rt)
        #pragma unroll
        for (int ct = 0; ct < 2; ++ct)
            #pragma unroll
            for (int rr = 0; rr < 4; ++rr) {
                int row = m0 + 64 * wr + 16 * rt + (lane >> 4) * 4 + rr;
                int col = p0 + 32 * wc + 16 * ct + (lane & 15);
                unsafeAtomicAdd(&acc[row * MI + col], accr[rt][ct][rr]);
            }
}

// psi2/Kuu/G build (blocks 0..255) fused with reduce_r (blocks 256..261)
__global__ __launch_bounds__(256) void k_psi2r(const float* __restrict__ Zg, const float* __restrict__ kvar,
                                               const float* __restrict__ klen, const float* __restrict__ lvar,
                                               const float* __restrict__ acc, float* __restrict__ psi2,
                                               float* __restrict__ Kuu, float* __restrict__ G,
                                               const float* __restrict__ rpart, float* __restrict__ r) {
    if (blockIdx.x >= 256) {
        int idx = (blockIdx.x - 256) * 256 + threadIdx.x;   // 0..1535
        if (idx < 1536) {
            float s = 0.f;
            for (int b = 0; b < 512; ++b) s += rpart[b * 1536 + idx];
            r[idx] = s;
        }
        return;
    }
    __shared__ float zi[D60];
    const int i = blockIdx.x, j = threadIdx.x;
    if (j < D60) zi[j] = Zg[i * D60 + j];
    __syncthreads();
    const float sf2 = kvar[0];
    const float l = klen[0];
    const float l2 = l * l;
    const float sigma2 = lvar[0];
    float zz = 0.f;
    #pragma unroll 10
    for (int d = 0; d < D60; ++d) {
        float dz = zi[d] - Zg[j * D60 + d];
        zz += dz * dz;
    }
    float accv = (i < 128 || j >= 128) ? acc[i * MI + j] : acc[j * MI + i];
    float p2 = sf2 * sf2 * __expf(-zz / (4.f * l2)) * accv;
    psi2[i * MI + j] = p2;
    float kv = sf2 * __expf(-0.5f * zz / l2) + ((i == j) ? JITTER : 0.f);
    Kuu[i * MI + j] = kv;
    G[i * MI + j] = kv + p2 / sigma2;
}

// concurrent 2-matrix Cholesky, merged-barrier ladder at 1024 threads with DIVISOR-FREE
// elimination indexing: thread = (row t&255, col-offset t>>8); per column-step each thread
// does one guarded row x <=8 independent col iterations (c += 4) — no runtime int div/mod
// (the old idx/rows,idx%rows compiled to ~150-cyc rcp sequences x8 iters = the real cost;
// round-17 proved barriers alone aren't it, round-15 proved single-wave LDS latency isn't
// viable either).
__global__ __launch_bounds__(1024) void k_chol2(float* __restrict__ A0, float* __restrict__ A1,
                                                float* __restrict__ At0, float* __restrict__ At1,
                                                float* __restrict__ scal) {
    float* A  = blockIdx.x ? A1 : A0;
    float* At = blockIdx.x ? At1 : At0;
    __shared__ float Pt[32][MI];   // Pt[c][r] = A[p+r][p+c]
    __shared__ float dsh[32];      // 1/d_jj
    const int t = threadIdx.x;
    const int ri = t & 255;        // elimination row offset
    const int cof = t >> 8;        // elimination col offset 0..3
    float lgacc = 0.f;
    for (int p = 0; p < MI; p += 32) {
        const int R = MI - p;
        for (int idx = t; idx < R * 32; idx += 1024) {
            int c = idx / R, rr = idx - c * R;
            Pt[c][rr] = A[(p + rr) * MI + (p + c)];
        }
        __syncthreads();
        for (int jj = 0; jj < 31; ++jj) {
            const float invd = 1.0f / fmaxf(Pt[jj][jj], 1e-20f);
            const int rr = jj + 1 + ri;
            if (rr < R) {
                const float pr = Pt[jj][rr] * invd;
                #pragma unroll 1
                for (int c = jj + 1 + cof; c < 32; c += 4)
                    Pt[c][rr] -= pr * Pt[jj][c];
            }
            __syncthreads();
        }
        if (t < 32) {
            float d = fmaxf(Pt[t][t], 1e-20f);
            dsh[t] = 1.0f / d;
            lgacc += __logf(d);
        }
        for (int idx = t; idx < R * 32; idx += 1024) {
            int c = idx / R, rr = idx - c * R;
            if (rr >= c) {
                float rs = rsqrtf(fmaxf(Pt[c][c], 1e-20f));
                At[(p + c) * MI + (p + rr)] = Pt[c][rr] * rs;
            }
        }
        __syncthreads();
        const int T = R - 32;
        if (T > 0) {
            const int BT = T >> 2;
            const int nb = BT * (BT + 1) / 2;
            for (int b = t; b < nb; b += 1024) {
                int br = (int)((sqrtf(8.0f * b + 1.0f) - 1.0f) * 0.5f);
                while ((br + 1) * (br + 2) / 2 <= b) ++br;
                while (br * (br + 1) / 2 > b) --br;
                int bc = b - br * (br + 1) / 2;
                int r0 = 32 + br * 4, c0 = 32 + bc * 4;
                float s[4][4];
                #pragma unroll
                for (int i = 0; i < 4; ++i)
                    #pragma unroll
                    for (int j = 0; j < 4; ++j) s[i][j] = 0.f;
                #pragma unroll 8
                for (int kk = 0; kk < 32; ++kk) {
                    float idk = dsh[kk];
                    float4 av = *(const float4*)(&Pt[kk][r0]);
                    float4 bv = *(const float4*)(&Pt[kk][c0]);
                    float aa[4] = {av.x, av.y, av.z, av.w};
                    float bb[4] = {bv.x * idk, bv.y * idk, bv.z * idk, bv.w * idk};
                    #pragma unroll
                    for (int i = 0; i < 4; ++i)
                        #pragma unroll
                        for (int j = 0; j < 4; ++j) s[i][j] += aa[i] * bb[j];
                }
                #pragma unroll
                for (int i = 0; i < 4; ++i)
                    #pragma unroll
                    for (int j = 0; j < 4; ++j)
                        A[(p + r0 + i) * MI + (p + c0 + j)] -= s[i][j];
            }
        }
        __syncthreads();
    }
    if (t < 32) {
        float v = lgacc;
        #pragma unroll
        for (int o = 16; o; o >>= 1) v += __shfl_down(v, o);
        if (t == 0) scal[5 + blockIdx.x] = v;   // = sum log d = 2*sum log diag(L)
    }
}

// wave-parallel forward triangular solve: L x = b for NQ RHS, single 64-lane wave,
// lane owns rows 4*lane..4*lane+3. At = L^T (coalesced column access). Returns sum of x^2.
template<int NQ, bool WTI>
__device__ __forceinline__ float tri_fwd(const float* __restrict__ At, float* __restrict__ Ti,
                                         int j0, float (&acc)[4][NQ]) {
    const int lane = threadIdx.x & 63;
    const int r0 = lane * 4;
    float invd[4];
    #pragma unroll
    for (int s = 0; s < 4; ++s) invd[s] = 1.0f / At[(r0 + s) * MI + (r0 + s)];
    float4 col[4];
    #pragma unroll
    for (int s = 0; s < 4; ++s) col[s] = *(const float4*)(At + (j0 + s) * MI + r0);
    float cs = 0.f;
    for (int i4 = j0; i4 < MI; i4 += 4) {
        float4 ncol[4];
        const bool more = (i4 + 4 < MI);
        #pragma unroll
        for (int s = 0; s < 4; ++s)
            ncol[s] = more ? *(const float4*)(At + (i4 + 4 + s) * MI + r0)
                           : make_float4(0.f, 0.f, 0.f, 0.f);
        #pragma unroll
        for (int S = 0; S < 4; ++S) {
            const int i = i4 + S;
            const int src = i >> 2;
            float xi[NQ];
            #pragma unroll
            for (int q = 0; q < NQ; ++q)
                xi[q] = __shfl(acc[S][q] * invd[S], src);
            if (WTI) {
                if (lane == src) {
                    #pragma unroll
                    for (int q = 0; q < NQ; ++q) Ti[i * MI + j0 + q] = xi[q];
                }
            }
            const float lv0 = col[S].x, lv1 = col[S].y, lv2 = col[S].z, lv3 = col[S].w;
            #pragma unroll
            for (int q = 0; q < NQ; ++q) {
                acc[0][q] -= lv0 * xi[q];
                acc[1][q] -= lv1 * xi[q];
                acc[2][q] -= lv2 * xi[q];
                acc[3][q] -= lv3 * xi[q];
                cs += xi[q] * xi[q];
            }
        }
        #pragma unroll
        for (int s = 0; s < 4; ++s) col[s] = ncol[s];
    }
    return cs;
}

// L^{-1} for Kuu: 16 blocks x 16 columns each. (Ti upper never read: tracedot guards.)
__global__ __launch_bounds__(64) void k_trinvK(const float* __restrict__ At, float* __restrict__ Ti) {
    const int lane = threadIdx.x;
    const int j0 = blockIdx.x * 16;
    const int r0 = lane * 4;
    float acc[4][16];
    #pragma unroll
    for (int s = 0; s < 4; ++s)
        #pragma unroll
        for (int q = 0; q < 16; ++q)
            acc[s][q] = (r0 + s == j0 + q) ? 1.f : 0.f;
    tri_fwd<16, true>(At, Ti, j0, acc);
}

// trace(Kuu^{-1} psi2) = sum_k v_k^T psi2 v_k, v_k = row k of Linv (lower; guard col>k)
__global__ __launch_bounds__(256) void k_tracedot(const float* __restrict__ Ti, const float* __restrict__ psi2,
                                                  float* __restrict__ scal) {
    __shared__ float vsh[MI];
    __shared__ float red[4];
    const int k = blockIdx.x, t = threadIdx.x;
    vsh[t] = Ti[k * MI + t];
    __syncthreads();
    float vj = (t <= k) ? vsh[t] : 0.f;
    float s = 0.f;
    for (int i = 0; i <= k; ++i) s += vsh[i] * psi2[i * MI + t];
    s *= vj;
    #pragma unroll
    for (int o = 32; o; o >>= 1) s += __shfl_down(s, o);
    if ((t & 63) == 0) red[t >> 6] = s;
    __syncthreads();
    if (t == 0) unsafeAtomicAdd(&scal[4], red[0] + red[1] + red[2] + red[3]);
}

// csum = sum_q || LG^{-1} r_q ||^2 via wave solve; lane 0 assembles final bound
__global__ __launch_bounds__(64) void k_solveG_final(const float* __restrict__ GT, const float* __restrict__ r,
                                                     const float* __restrict__ scal,
                                                     const float* __restrict__ kvar,
                                                     const float* __restrict__ lvar, const int* __restrict__ ltp,
                                                     float* __restrict__ out) {
    const int lane = threadIdx.x;
    const int r0 = lane * 4;
    float acc[4][QD];
    #pragma unroll
    for (int s = 0; s < 4; ++s)
        #pragma unroll
        for (int q = 0; q < QD; ++q)
            acc[s][q] = r[(r0 + s) * QD + q];
    float cs = tri_fwd<QD, false>(GT, nullptr, 0, acc);
    if (lane == 0) {
        double csum = (double)cs;
        double sigma2 = (double)lvar[0];
        double sf2 = (double)kvar[0];
        double two_pi = 6.283185307179586;
        double Nw = (double)NW, Q = (double)QD;
        double psi0 = Nw * sf2;
        double trace_AAT = (double)scal[4] / sigma2;
        double logdetB = (double)scal[6] - (double)scal[5];
        double bound = -0.5 * Nw * Q * log(two_pi * sigma2);
        bound += -0.5 / sigma2 * ((double)scal[0] + (double)scal[1]);
        bound += -0.5 * Q * (psi0 / sigma2 - trace_AAT);
        bound += -0.5 * Q * logdetB;
        bound += 0.5 * csum / (sigma2 * sigma2);
        bound += 0.5 * (double)scal[2] + Nw * Q * 0.5 * log(two_pi);
        bound += -(double)ltp[0] * Q * log(two_pi) - 0.5 * (double)scal[3];
        out[0] = (float)bound;
    }
}

extern "C" void kernel_launch(void* const* d_in, const int* in_sizes, int n_in,
                              void* d_out, int out_size, void* d_ws, size_t ws_size,
                              hipStream_t stream) {
    (void)in_sizes; (void)n_in; (void)out_size; (void)ws_size;
    const float* Xm = (const float*)d_in[0];
    const float* Xv = (const float*)d_in[1];
    const float* Zg = (const float*)d_in[2];
    const float* kvar = (const float*)d_in[3];
    const float* klen = (const float*)d_in[4];
    const float* lvar = (const float*)d_in[5];
    const int* ltp = (const int*)d_in[6];
    float* ws = (float*)d_ws;
    float* W = ws + OFF_W;
    float* Slog = ws + OFF_SLOG;
    float* acc = ws + OFF_ACC;
    float* Kuu = ws + OFF_KUU;
    float* G = ws + OFF_G;
    float* psi2 = ws + OFF_PSI2;
    float* rpart = ws + OFF_RPART;
    float* r = ws + OFF_R;
    float* scal = ws + OFF_SCAL;
    float* Ti1 = ws + OFF_TI1;
    float* KT = ws + OFF_KT;
    float* GT = ws + OFF_GT;

    hipMemsetAsync(scal, 0, 16 * sizeof(float), stream);   // includes q[8] at scal+8

    k_prep<<<512, 256, 0, stream>>>(Xm, Xv, Zg, kvar, klen, W, Slog, rpart, acc, scal);
    k_acc<<<768, 256, 0, stream>>>(Zg, W, Slog, acc, (int*)(scal + 8));
    k_psi2r<<<262, 256, 0, stream>>>(Zg, kvar, klen, lvar, acc, psi2, Kuu, G, rpart, r);
    k_chol2<<<2, 1024, 0, stream>>>(Kuu, G, KT, GT, scal);
    k_trinvK<<<16, 64, 0, stream>>>(KT, Ti1);
    k_tracedot<<<256, 256, 0, stream>>>(Ti1, psi2, scal);
    k_solveG_final<<<1, 64, 0, stream>>>(GT, r, scal, kvar, lvar, ltp, (float*)d_out);
}

// Round 19
// 633.482 us; speedup vs baseline: 2.0601x; 1.0627x over previous
//
#include <hip/hip_runtime.h>
#include <math.h>

#define QD 6
#define LTC 10
#define NW 8192
#define NT (NW + LTC)      // 8202
#define D60 60
#define MI 256
#define JITTER 1e-6f
#define LOG2E 1.4426950408889634f

typedef __attribute__((ext_vector_type(8))) short bf16x8;
typedef __attribute__((ext_vector_type(4))) float f32x4;

// ws layout (float offsets)
#define OFF_W      0                       // 8192*64
#define OFF_SLOG   524288                  // 8192*256 (reused post-k_acc: KT/GT)
#define OFF_ACC    (OFF_SLOG + 2097152)    // 65536
#define OFF_KUU    (OFF_ACC + 65536)
#define OFF_G      (OFF_KUU + 65536)
#define OFF_PSI2   (OFF_G + 65536)
#define OFF_RPART  (OFF_PSI2 + 65536)      // 512*256*6
#define OFF_R      (OFF_RPART + 786432)    // 1536
#define OFF_SCAL   (OFF_R + 1536)          // 16 (floats; [8..15] = k_acc work-queue ints)
#define OFF_TI1    (OFF_SCAL + 16)         // 65536
// aliases into dead Slog region (only used after k_acc completes):
#define OFF_KT     OFF_SLOG                // 65536
#define OFF_GT     (OFF_SLOG + 65536)      // 65536
// scal: 0 sumXvo, 1 sumXmo2, 2 sumlogXvo, 3 summb, 4 trace_raw, 5 ldK, 6 ldG

__device__ __forceinline__ ushort f2bf(float f) {
    union { float f; unsigned u; } x; x.f = f;
    unsigned r = x.u + 0x7fffu + ((x.u >> 16) & 1u);
    return (ushort)(r >> 16);
}
__device__ __forceinline__ float bf2f(ushort h) {
    return __uint_as_float(((unsigned)h) << 16);
}
__device__ __forceinline__ unsigned cvt_pk_bf16(float a, float b) {
    unsigned r;
    asm("v_cvt_pk_bf16_f32 %0, %1, %2" : "=v"(r) : "v"(a), "v"(b));
    return r;   // lo16 = bf16(a), hi16 = bf16(b), RNE
}

// prep: fused {acc zeroing, reduce_x (blocks<64)}, wave-local phase-1, 1 barrier, phase-2
__global__ __launch_bounds__(256) void k_prep(const float* __restrict__ Xm, const float* __restrict__ Xv,
                                              const float* __restrict__ Zg, const float* __restrict__ kvar,
                                              const float* __restrict__ klen,
                                              float* __restrict__ W, float* __restrict__ Slog,
                                              float* __restrict__ rpart,
                                              float* __restrict__ accz, float* __restrict__ scal) {
    __shared__ float Zt[D60][MI];            // 61.4 KB
    __shared__ float4 quadS[16][D60];        // {w*mu, w, 1/(S+l2), mu}
    __shared__ float sldS[16][2];
    __shared__ float xmoS[16][QD];
    __shared__ float redx[4][4];
    const int t = threadIdx.x;
    // fused acc zeroing (512 blocks x 128 = 65536)
    if (t < 128) accz[blockIdx.x * 128 + t] = 0.f;
    // fused reduce_x (blocks 0..63 only; block-uniform barrier use)
    if (blockIdx.x < 64) {
        float s0 = 0.f, s1 = 0.f, s2 = 0.f, s3 = 0.f;
        const int tot = NT * QD;
        for (int i = blockIdx.x * 256 + t; i < tot; i += 64 * 256) {
            float xm = Xm[i], xv = Xv[i];
            if (i >= LTC * QD) { s0 += xv; s1 += xm * xm; s2 += __logf(xv); }
            else { s3 += xm * xm + xv; }
        }
        #pragma unroll
        for (int o = 32; o; o >>= 1) {
            s0 += __shfl_down(s0, o); s1 += __shfl_down(s1, o);
            s2 += __shfl_down(s2, o); s3 += __shfl_down(s3, o);
        }
        if ((t & 63) == 0) { int w = t >> 6; redx[0][w] = s0; redx[1][w] = s1; redx[2][w] = s2; redx[3][w] = s3; }
        __syncthreads();
        if (t == 0) {
            float a0 = 0, a1 = 0, a2 = 0, a3 = 0;
            for (int w = 0; w < 4; ++w) { a0 += redx[0][w]; a1 += redx[1][w]; a2 += redx[2][w]; a3 += redx[3][w]; }
            unsafeAtomicAdd(&scal[0], a0); unsafeAtomicAdd(&scal[1], a1);
            unsafeAtomicAdd(&scal[2], a2); unsafeAtomicAdd(&scal[3], a3);
        }
    }
    const float sf2 = kvar[0];
    const float l = klen[0];
    const float l2 = l * l;
    for (int idx = t; idx < D60 * MI; idx += 256) {
        int d = idx >> 8, m = idx & 255;
        Zt[d][m] = Zg[m * D60 + d];
    }
    const int n0 = blockIdx.x * 16;
    const int wv = t >> 6, lane = t & 63;
    #pragma unroll
    for (int i = 0; i < 4; ++i) {
        const int nn = wv * 4 + i;
        const int n = n0 + nn;
        float lt1 = 0.f, lt2 = 0.f, e1 = 0.f;
        if (lane < D60) {
            float S = Xv[n * QD + lane], mu = Xm[n * QD + lane];
            float w = 1.0f / (2.0f * S + l2);
            float invd1 = 1.0f / (S + l2);
            quadS[nn][lane] = make_float4(w * mu, w, invd1, mu);
            W[n * 64 + lane] = -0.5f * LOG2E * w;
            lt1 = __logf(1.0f + S / l2);
            lt2 = __logf(1.0f + 2.0f * S / l2);
            e1 = w * mu * mu;
        } else {
            W[n * 64 + lane] = 0.f;
        }
        if (lane < QD) xmoS[nn][lane] = Xm[n * QD + D60 + lane];
        #pragma unroll
        for (int o = 32; o; o >>= 1) {
            lt1 += __shfl_down(lt1, o); lt2 += __shfl_down(lt2, o); e1 += __shfl_down(e1, o);
        }
        if (lane == 0) { sldS[nn][0] = -0.5f * lt1; sldS[nn][1] = 0.5f * (-0.5f * lt2 - e1); }
    }
    __syncthreads();
    float r6[QD];
    #pragma unroll
    for (int q = 0; q < QD; ++q) r6[q] = 0.f;
    for (int nn = 0; nn < 16; ++nn) {
        const int n = n0 + nn;
        float e2 = 0.f, e3 = 0.f, q1 = 0.f;
        #pragma unroll 10
        for (int d = 0; d < D60; ++d) {
            float4 qd = quadS[nn][d];
            float z = Zt[d][t];
            e2 += qd.x * z;
            e3 += qd.y * z * z;
            float dm = qd.w - z;
            q1 += dm * dm * qd.z;
        }
        Slog[n * MI + t] = sldS[nn][1] + e2 - 0.25f * e3;
        float psi1 = sf2 * __expf(sldS[nn][0] - 0.5f * q1);
        #pragma unroll
        for (int q = 0; q < QD; ++q) r6[q] += psi1 * xmoS[nn][q];
    }
    #pragma unroll
    for (int q = 0; q < QD; ++q) rpart[(blockIdx.x * MI + t) * QD + q] = r6[q];
}

// main: acc[m,p] += sum_n exp2( LOG2E*(Slog_a+Slog_b) - LOG2E*e4 ).
// OPERAND SWAP (round 19): A = Z_m STATIC (hi/lo frags in registers, loaded once);
// B = W*Z_p DYNAMIC (only 64x64 staged per n — half the old staging work/writes).
// Same 3-pass split (Ah*Bh + Ah*Bl + Al*Bh); identical error class (lo*lo dropped).
// B LDS buffers alias the dead A-prologue region — LDS stays 50 KB, 3 blocks/CU.
__global__ __launch_bounds__(256, 2) void k_acc(const float* __restrict__ Zg, const float* __restrict__ W,
                                                const float* __restrict__ Slog, float* __restrict__ acc,
                                                int* __restrict__ q) {
    __shared__ ushort Ah[128 * 64];   // 16 KB: prologue A-hi; first 16KB reused as Bh/Bl
    __shared__ ushort Al[128 * 64];   // 16 KB: prologue A-lo (dead after frag load)
    __shared__ float Wlds[64 * 64];   // 16 KB: W[n0+nn][d]
    __shared__ float saa[128], sbb[64];
    __shared__ int wksh;
    char* const Bh = (char*)Ah;            // 8 KB alias
    char* const Bl = (char*)Ah + 8192;     // 8 KB alias
    const int t = threadIdx.x;
    if (t == 0) {
        int xcc = (int)(__builtin_amdgcn_s_getreg((31 << 11) | 20)) & 7;   // HW_REG_XCC_ID
        int work = 0;
        #pragma unroll 1
        for (int a = 0; a < 8; ++a) {
            int p = (xcc + a) & 7;
            int tk = atomicAdd(&q[p], 1);
            if (tk < 96) { work = p * 96 + tk; break; }
        }
        wksh = work;
    }
    __syncthreads();
    const int wk = wksh;
    const int nc = wk / 6;
    const int tile = wk % 6;
    const int m0 = (tile < 4) ? 0 : 128;
    const int p0 = (tile < 4) ? tile * 64 : 128 + (tile - 4) * 64;
    const int lane = t & 63, wid = t >> 6;
    const int wr = wid >> 1, wc = wid & 1;
    const int n0 = nc * 64;

    // stage W window and static A-side (Z_m, 128 rows) hi/lo
    for (int idx = t; idx < 64 * 64; idx += 256)
        Wlds[idx] = W[n0 * 64 + idx];
    for (int idx = t; idx < 128 * 64; idx += 256) {
        int m = idx >> 6, k = idx & 63;
        float v = (k < D60) ? Zg[(m0 + m) * D60 + k] : 0.f;
        ushort hi = f2bf(v);
        ushort lo = f2bf(v - bf2f(hi));
        int byte = m * 128 + ((k * 2) ^ ((m & 7) << 4));
        *(ushort*)((char*)Ah + byte) = hi;
        *(ushort*)((char*)Al + byte) = lo;
    }
    __syncthreads();
    // load static A fragments into registers (16 x bf16x8 = 64 VGPR)
    bf16x8 afh[4][2], afl[4][2];
    #pragma unroll
    for (int rt = 0; rt < 4; ++rt) {
        int m = 64 * wr + 16 * rt + (lane & 15);
        int swz = (m & 7) << 4;
        #pragma unroll
        for (int h = 0; h < 2; ++h) {
            int byte = m * 128 + ((((lane >> 4) * 16) + 64 * h) ^ swz);
            afh[rt][h] = *(const bf16x8*)((const char*)Ah + byte);
            afl[rt][h] = *(const bf16x8*)((const char*)Al + byte);
        }
    }
    // per-thread B-side z values: row pb = t>>2, cols kb0..kb0+15 (pinned)
    const int pb = t >> 2;
    const int kb0 = (t & 3) * 16;
    float zb[16];
    #pragma unroll
    for (int j = 0; j < 16; ++j) {
        int k = kb0 + j;
        zb[j] = (k < D60) ? Zg[(p0 + pb) * D60 + k] : 0.f;
        asm volatile("" : "+v"(zb[j]));
    }

    float accr[4][2][4];
    #pragma unroll
    for (int a = 0; a < 4; ++a)
        #pragma unroll
        for (int b = 0; b < 2; ++b)
            #pragma unroll
            for (int c = 0; c < 4; ++c) accr[a][b][c] = 0.f;

    const int bswz = (pb & 7) << 4;
    const int bb0 = pb * 128 + ((kb0 * 2) ^ bswz);
    const int bb1 = pb * 128 + ((kb0 * 2 + 16) ^ bswz);
    for (int nn = 0; nn < 64; ++nn) {
        const int n = n0 + nn;
        __syncthreads();   // previous compute done reading Bh/Bl (first iter: A-frag loads done)
        // ---- stage B = W[nn] * Z_p (64x64) hi/lo ----
        {
            const float* wrow = Wlds + nn * 64 + kb0;
            float bv[16];
            #pragma unroll
            for (int j = 0; j < 4; ++j) {
                float4 f = *(const float4*)(wrow + 4 * j);
                bv[4 * j + 0] = f.x * zb[4 * j + 0];
                bv[4 * j + 1] = f.y * zb[4 * j + 1];
                bv[4 * j + 2] = f.z * zb[4 * j + 2];
                bv[4 * j + 3] = f.w * zb[4 * j + 3];
            }
            unsigned ph[8], pl[8];
            #pragma unroll
            for (int j = 0; j < 8; ++j) {
                float v0 = bv[2 * j], v1 = bv[2 * j + 1];
                unsigned u = cvt_pk_bf16(v0, v1);
                float h0 = __uint_as_float(u << 16);
                float h1 = __uint_as_float(u & 0xffff0000u);
                ph[j] = u;
                pl[j] = cvt_pk_bf16(v0 - h0, v1 - h1);
            }
            uint4 v0h; v0h.x = ph[0]; v0h.y = ph[1]; v0h.z = ph[2]; v0h.w = ph[3];
            uint4 v1h; v1h.x = ph[4]; v1h.y = ph[5]; v1h.z = ph[6]; v1h.w = ph[7];
            uint4 v0l; v0l.x = pl[0]; v0l.y = pl[1]; v0l.z = pl[2]; v0l.w = pl[3];
            uint4 v1l; v1l.x = pl[4]; v1l.y = pl[5]; v1l.z = pl[6]; v1l.w = pl[7];
            *(uint4*)(Bh + bb0) = v0h;
            *(uint4*)(Bh + bb1) = v1h;
            *(uint4*)(Bl + bb0) = v0l;
            *(uint4*)(Bl + bb1) = v1l;
            if (t < 128) saa[t] = LOG2E * Slog[n * MI + m0 + t];
            else if (t < 192) sbb[t - 128] = LOG2E * Slog[n * MI + p0 + (t - 128)];
        }
        __syncthreads();
        // ---- compute ----
        bf16x8 bfh[2][2], bfl[2][2];
        #pragma unroll
        for (int ct = 0; ct < 2; ++ct) {
            int p = 32 * wc + 16 * ct + (lane & 15);
            int swz = (p & 7) << 4;
            #pragma unroll
            for (int h = 0; h < 2; ++h) {
                int byte = p * 128 + ((((lane >> 4) * 16) + 64 * h) ^ swz);
                bfh[ct][h] = *(const bf16x8*)(Bh + byte);
                bfl[ct][h] = *(const bf16x8*)(Bl + byte);
            }
        }
        float sbv[2];
        #pragma unroll
        for (int ct = 0; ct < 2; ++ct) sbv[ct] = sbb[32 * wc + 16 * ct + (lane & 15)];
        #pragma unroll
        for (int rt = 0; rt < 4; ++rt) {
            float sav[4];
            int rbase = 64 * wr + 16 * rt + (lane >> 4) * 4;
            #pragma unroll
            for (int rr = 0; rr < 4; ++rr) sav[rr] = saa[rbase + rr];
            #pragma unroll
            for (int ct = 0; ct < 2; ++ct) {
                f32x4 d;
                #pragma unroll
                for (int rr = 0; rr < 4; ++rr) d[rr] = sav[rr] + sbv[ct];
                d = __builtin_amdgcn_mfma_f32_16x16x32_bf16(afh[rt][0], bfh[ct][0], d, 0, 0, 0);
                d = __builtin_amdgcn_mfma_f32_16x16x32_bf16(afh[rt][1], bfh[ct][1], d, 0, 0, 0);
                d = __builtin_amdgcn_mfma_f32_16x16x32_bf16(afh[rt][0], bfl[ct][0], d, 0, 0, 0);
                d = __builtin_amdgcn_mfma_f32_16x16x32_bf16(afh[rt][1], bfl[ct][1], d, 0, 0, 0);
                d = __builtin_amdgcn_mfma_f32_16x16x32_bf16(afl[rt][0], bfh[ct][0], d, 0, 0, 0);
                d = __builtin_amdgcn_mfma_f32_16x16x32_bf16(afl[rt][1], bfh[ct][1], d, 0, 0, 0);
                #pragma unroll
                for (int rr = 0; rr < 4; ++rr)
                    accr[rt][ct][rr] += exp2f(d[rr]);
            }
        }
    }
    #pragma unroll
    for (int rt = 0; rt < 4; ++rt)
        #pragma unroll
        for (int ct = 0; ct < 2; ++ct)
            #pragma unroll
            for (int rr = 0; rr < 4; ++rr) {
                int row = m0 + 64 * wr + 16 * rt + (lane >> 4) * 4 + rr;
                int col = p0 + 32 * wc + 16 * ct + (lane & 15);
                unsafeAtomicAdd(&acc[row * MI + col], accr[rt][ct][rr]);
            }
}

// psi2/Kuu/G build (blocks 0..255) fused with reduce_r (blocks 256..261)
__global__ __launch_bounds__(256) void k_psi2r(const float* __restrict__ Zg, const float* __restrict__ kvar,
                                               const float* __restrict__ klen, const float* __restrict__ lvar,
                                               const float* __restrict__ acc, float* __restrict__ psi2,
                                               float* __restrict__ Kuu, float* __restrict__ G,
                                               const float* __restrict__ rpart, float* __restrict__ r) {
    if (blockIdx.x >= 256) {
        int idx = (blockIdx.x - 256) * 256 + threadIdx.x;   // 0..1535
        if (idx < 1536) {
            float s = 0.f;
            for (int b = 0; b < 512; ++b) s += rpart[b * 1536 + idx];
            r[idx] = s;
        }
        return;
    }
    __shared__ float zi[D60];
    const int i = blockIdx.x, j = threadIdx.x;
    if (j < D60) zi[j] = Zg[i * D60 + j];
    __syncthreads();
    const float sf2 = kvar[0];
    const float l = klen[0];
    const float l2 = l * l;
    const float sigma2 = lvar[0];
    float zz = 0.f;
    #pragma unroll 10
    for (int d = 0; d < D60; ++d) {
        float dz = zi[d] - Zg[j * D60 + d];
        zz += dz * dz;
    }
    float accv = (i < 128 || j >= 128) ? acc[i * MI + j] : acc[j * MI + i];
    float p2 = sf2 * sf2 * __expf(-zz / (4.f * l2)) * accv;
    psi2[i * MI + j] = p2;
    float kv = sf2 * __expf(-0.5f * zz / l2) + ((i == j) ? JITTER : 0.f);
    Kuu[i * MI + j] = kv;
    G[i * MI + j] = kv + p2 / sigma2;
}

// concurrent 2-matrix Cholesky, merged-barrier ladder at 1024 threads, divisor-free
// elimination indexing (round 18, verified).
__global__ __launch_bounds__(1024) void k_chol2(float* __restrict__ A0, float* __restrict__ A1,
                                                float* __restrict__ At0, float* __restrict__ At1,
                                                float* __restrict__ scal) {
    float* A  = blockIdx.x ? A1 : A0;
    float* At = blockIdx.x ? At1 : At0;
    __shared__ float Pt[32][MI];   // Pt[c][r] = A[p+r][p+c]
    __shared__ float dsh[32];      // 1/d_jj
    const int t = threadIdx.x;
    const int ri = t & 255;        // elimination row offset
    const int cof = t >> 8;        // elimination col offset 0..3
    float lgacc = 0.f;
    for (int p = 0; p < MI; p += 32) {
        const int R = MI - p;
        for (int idx = t; idx < R * 32; idx += 1024) {
            int c = idx / R, rr = idx - c * R;
            Pt[c][rr] = A[(p + rr) * MI + (p + c)];
        }
        __syncthreads();
        for (int jj = 0; jj < 31; ++jj) {
            const float invd = 1.0f / fmaxf(Pt[jj][jj], 1e-20f);
            const int rr = jj + 1 + ri;
            if (rr < R) {
                const float pr = Pt[jj][rr] * invd;
                #pragma unroll 1
                for (int c = jj + 1 + cof; c < 32; c += 4)
                    Pt[c][rr] -= pr * Pt[jj][c];
            }
            __syncthreads();
        }
        if (t < 32) {
            float d = fmaxf(Pt[t][t], 1e-20f);
            dsh[t] = 1.0f / d;
            lgacc += __logf(d);
        }
        for (int idx = t; idx < R * 32; idx += 1024) {
            int c = idx / R, rr = idx - c * R;
            if (rr >= c) {
                float rs = rsqrtf(fmaxf(Pt[c][c], 1e-20f));
                At[(p + c) * MI + (p + rr)] = Pt[c][rr] * rs;
            }
        }
        __syncthreads();
        const int T = R - 32;
        if (T > 0) {
            const int BT = T >> 2;
            const int nb = BT * (BT + 1) / 2;
            for (int b = t; b < nb; b += 1024) {
                int br = (int)((sqrtf(8.0f * b + 1.0f) - 1.0f) * 0.5f);
                while ((br + 1) * (br + 2) / 2 <= b) ++br;
                while (br * (br + 1) / 2 > b) --br;
                int bc = b - br * (br + 1) / 2;
                int r0 = 32 + br * 4, c0 = 32 + bc * 4;
                float s[4][4];
                #pragma unroll
                for (int i = 0; i < 4; ++i)
                    #pragma unroll
                    for (int j = 0; j < 4; ++j) s[i][j] = 0.f;
                #pragma unroll 8
                for (int kk = 0; kk < 32; ++kk) {
                    float idk = dsh[kk];
                    float4 av = *(const float4*)(&Pt[kk][r0]);
                    float4 bv = *(const float4*)(&Pt[kk][c0]);
                    float aa[4] = {av.x, av.y, av.z, av.w};
                    float bb[4] = {bv.x * idk, bv.y * idk, bv.z * idk, bv.w * idk};
                    #pragma unroll
                    for (int i = 0; i < 4; ++i)
                        #pragma unroll
                        for (int j = 0; j < 4; ++j) s[i][j] += aa[i] * bb[j];
                }
                #pragma unroll
                for (int i = 0; i < 4; ++i)
                    #pragma unroll
                    for (int j = 0; j < 4; ++j)
                        A[(p + r0 + i) * MI + (p + c0 + j)] -= s[i][j];
            }
        }
        __syncthreads();
    }
    if (t < 32) {
        float v = lgacc;
        #pragma unroll
        for (int o = 16; o; o >>= 1) v += __shfl_down(v, o);
        if (t == 0) scal[5 + blockIdx.x] = v;   // = sum log d = 2*sum log diag(L)
    }
}

// wave-parallel forward triangular solve: L x = b for NQ RHS, single 64-lane wave,
// lane owns rows 4*lane..4*lane+3. At = L^T (coalesced column access). Returns sum of x^2.
template<int NQ, bool WTI>
__device__ __forceinline__ float tri_fwd(const float* __restrict__ At, float* __restrict__ Ti,
                                         int j0, float (&acc)[4][NQ]) {
    const int lane = threadIdx.x & 63;
    const int r0 = lane * 4;
    float invd[4];
    #pragma unroll
    for (int s = 0; s < 4; ++s) invd[s] = 1.0f / At[(r0 + s) * MI + (r0 + s)];
    float4 col[4];
    #pragma unroll
    for (int s = 0; s < 4; ++s) col[s] = *(const float4*)(At + (j0 + s) * MI + r0);
    float cs = 0.f;
    for (int i4 = j0; i4 < MI; i4 += 4) {
        float4 ncol[4];
        const bool more = (i4 + 4 < MI);
        #pragma unroll
        for (int s = 0; s < 4; ++s)
            ncol[s] = more ? *(const float4*)(At + (i4 + 4 + s) * MI + r0)
                           : make_float4(0.f, 0.f, 0.f, 0.f);
        #pragma unroll
        for (int S = 0; S < 4; ++S) {
            const int i = i4 + S;
            const int src = i >> 2;
            float xi[NQ];
            #pragma unroll
            for (int q = 0; q < NQ; ++q)
                xi[q] = __shfl(acc[S][q] * invd[S], src);
            if (WTI) {
                if (lane == src) {
                    #pragma unroll
                    for (int q = 0; q < NQ; ++q) Ti[i * MI + j0 + q] = xi[q];
                }
            }
            const float lv0 = col[S].x, lv1 = col[S].y, lv2 = col[S].z, lv3 = col[S].w;
            #pragma unroll
            for (int q = 0; q < NQ; ++q) {
                acc[0][q] -= lv0 * xi[q];
                acc[1][q] -= lv1 * xi[q];
                acc[2][q] -= lv2 * xi[q];
                acc[3][q] -= lv3 * xi[q];
                cs += xi[q] * xi[q];
            }
        }
        #pragma unroll
        for (int s = 0; s < 4; ++s) col[s] = ncol[s];
    }
    return cs;
}

// L^{-1} for Kuu: 16 blocks x 16 columns each. (Ti upper never read: tracedot guards.)
__global__ __launch_bounds__(64) void k_trinvK(const float* __restrict__ At, float* __restrict__ Ti) {
    const int lane = threadIdx.x;
    const int j0 = blockIdx.x * 16;
    const int r0 = lane * 4;
    float acc[4][16];
    #pragma unroll
    for (int s = 0; s < 4; ++s)
        #pragma unroll
        for (int q = 0; q < 16; ++q)
            acc[s][q] = (r0 + s == j0 + q) ? 1.f : 0.f;
    tri_fwd<16, true>(At, Ti, j0, acc);
}

// trace(Kuu^{-1} psi2) = sum_k v_k^T psi2 v_k, v_k = row k of Linv (lower; guard col>k)
__global__ __launch_bounds__(256) void k_tracedot(const float* __restrict__ Ti, const float* __restrict__ psi2,
                                                  float* __restrict__ scal) {
    __shared__ float vsh[MI];
    __shared__ float red[4];
    const int k = blockIdx.x, t = threadIdx.x;
    vsh[t] = Ti[k * MI + t];
    __syncthreads();
    float vj = (t <= k) ? vsh[t] : 0.f;
    float s = 0.f;
    for (int i = 0; i <= k; ++i) s += vsh[i] * psi2[i * MI + t];
    s *= vj;
    #pragma unroll
    for (int o = 32; o; o >>= 1) s += __shfl_down(s, o);
    if ((t & 63) == 0) red[t >> 6] = s;
    __syncthreads();
    if (t == 0) unsafeAtomicAdd(&scal[4], red[0] + red[1] + red[2] + red[3]);
}

// csum = sum_q || LG^{-1} r_q ||^2 via wave solve; lane 0 assembles final bound
__global__ __launch_bounds__(64) void k_solveG_final(const float* __restrict__ GT, const float* __restrict__ r,
                                                     const float* __restrict__ scal,
                                                     const float* __restrict__ kvar,
                                                     const float* __restrict__ lvar, const int* __restrict__ ltp,
                                                     float* __restrict__ out) {
    const int lane = threadIdx.x;
    const int r0 = lane * 4;
    float acc[4][QD];
    #pragma unroll
    for (int s = 0; s < 4; ++s)
        #pragma unroll
        for (int q = 0; q < QD; ++q)
            acc[s][q] = r[(r0 + s) * QD + q];
    float cs = tri_fwd<QD, false>(GT, nullptr, 0, acc);
    if (lane == 0) {
        double csum = (double)cs;
        double sigma2 = (double)lvar[0];
        double sf2 = (double)kvar[0];
        double two_pi = 6.283185307179586;
        double Nw = (double)NW, Q = (double)QD;
        double psi0 = Nw * sf2;
        double trace_AAT = (double)scal[4] / sigma2;
        double logdetB = (double)scal[6] - (double)scal[5];
        double bound = -0.5 * Nw * Q * log(two_pi * sigma2);
        bound += -0.5 / sigma2 * ((double)scal[0] + (double)scal[1]);
        bound += -0.5 * Q * (psi0 / sigma2 - trace_AAT);
        bound += -0.5 * Q * logdetB;
        bound += 0.5 * csum / (sigma2 * sigma2);
        bound += 0.5 * (double)scal[2] + Nw * Q * 0.5 * log(two_pi);
        bound += -(double)ltp[0] * Q * log(two_pi) - 0.5 * (double)scal[3];
        out[0] = (float)bound;
    }
}

extern "C" void kernel_launch(void* const* d_in, const int* in_sizes, int n_in,
                              void* d_out, int out_size, void* d_ws, size_t ws_size,
                              hipStream_t stream) {
    (void)in_sizes; (void)n_in; (void)out_size; (void)ws_size;
    const float* Xm = (const float*)d_in[0];
    const float* Xv = (const float*)d_in[1];
    const float* Zg = (const float*)d_in[2];
    const float* kvar = (const float*)d_in[3];
    const float* klen = (const float*)d_in[4];
    const float* lvar = (const float*)d_in[5];
    const int* ltp = (const int*)d_in[6];
    float* ws = (float*)d_ws;
    float* W = ws + OFF_W;
    float* Slog = ws + OFF_SLOG;
    float* acc = ws + OFF_ACC;
    float* Kuu = ws + OFF_KUU;
    float* G = ws + OFF_G;
    float* psi2 = ws + OFF_PSI2;
    float* rpart = ws + OFF_RPART;
    float* r = ws + OFF_R;
    float* scal = ws + OFF_SCAL;
    float* Ti1 = ws + OFF_TI1;
    float* KT = ws + OFF_KT;
    float* GT = ws + OFF_GT;

    hipMemsetAsync(scal, 0, 16 * sizeof(float), stream);   // includes q[8] at scal+8

    k_prep<<<512, 256, 0, stream>>>(Xm, Xv, Zg, kvar, klen, W, Slog, rpart, acc, scal);
    k_acc<<<768, 256, 0, stream>>>(Zg, W, Slog, acc, (int*)(scal + 8));
    k_psi2r<<<262, 256, 0, stream>>>(Zg, kvar, klen, lvar, acc, psi2, Kuu, G, rpart, r);
    k_chol2<<<2, 1024, 0, stream>>>(Kuu, G, KT, GT, scal);
    k_trinvK<<<16, 64, 0, stream>>>(KT, Ti1);
    k_tracedot<<<256, 256, 0, stream>>>(Ti1, psi2, scal);
    k_solveG_final<<<1, 64, 0, stream>>>(GT, r, scal, kvar, lvar, ltp, (float*)d_out);
}